// Round 1
// baseline (405.662 us; speedup 1.0000x reference)
//
#include <hip/hip_runtime.h>
#include <stdint.h>

// SpecAugment: out[b,t,f] = x[b,t,f] * keep(b,t,f)
// keep = !(freq_mask[f] | time_mask[b,t]), masks derived from JAX threefry2x32
// (seed 42), partitionable ("fold-like") counter scheme (JAX >= 0.4.30 default).
//
// B=128, T=4000, F=128 (fixed by the reference setup_inputs).

#define B_DIM 128
#define T_DIM 4000
#define F_DIM 128

typedef float f32x4 __attribute__((ext_vector_type(4)));

__device__ __forceinline__ uint32_t rotl32(uint32_t x, uint32_t d) {
  return (x << d) | (x >> (32u - d));
}

// JAX threefry2x32 block cipher (20 rounds).
__device__ __forceinline__ void threefry2x32(uint32_t k0, uint32_t k1,
                                             uint32_t x0, uint32_t x1,
                                             uint32_t& y0, uint32_t& y1) {
  const uint32_t ks[3] = {k0, k1, k0 ^ k1 ^ 0x1BD11BDAu};
  const uint32_t rotA[4] = {13u, 15u, 26u, 6u};
  const uint32_t rotB[4] = {17u, 29u, 16u, 24u};
  x0 += ks[0];
  x1 += ks[1];
#pragma unroll
  for (int i = 0; i < 5; ++i) {
#pragma unroll
    for (int j = 0; j < 4; ++j) {
      const uint32_t r = (i & 1) ? rotB[j] : rotA[j];
      x0 += x1;
      x1 = rotl32(x1, r);
      x1 ^= x0;
    }
    x0 += ks[(i + 1) % 3];
    x1 += ks[(i + 2) % 3] + (uint32_t)(i + 1);
  }
  y0 = x0;
  y1 = x1;
}

// Partitionable random bits: element index e -> xor of cipher outputs at
// 64-bit counter e (hi=0 for our sizes).
__device__ __forceinline__ uint32_t rbits(uint32_t k0, uint32_t k1, uint32_t e) {
  uint32_t y0, y1;
  threefry2x32(k0, k1, 0u, e, y0, y1);
  return y0 ^ y1;
}

// JAX uniform [0,1): bitcast((bits >> 9) | 0x3f800000) - 1.0f
__device__ __forceinline__ float u01(uint32_t bits) {
  const uint32_t fb = (bits >> 9) | 0x3f800000u;
  return __fsub_rn(__uint_as_float(fb), 1.0f);
}

// One block, 128 threads (thread b = batch index = frequency bin index).
// ws layout (floats): [0..127]   keepF[f]  (1.0 keep / 0.0 masked)
//                     [128..639] per-b float4 {ts0, te0, ts1, te1}
__global__ __launch_bounds__(128) void specaug_setup(
    const int* __restrict__ x_len, float* __restrict__ ws) {
  const int b = threadIdx.x;

  // split(key(42), 3) fold-like: key_i = cipher((0,42),(0,i))
  uint32_t kf0, kf1, kv0, kv1, ks0, ks1;
  threefry2x32(0u, 42u, 0u, 0u, kf0, kf1);
  threefry2x32(0u, 42u, 0u, 1u, kv0, kv1);
  threefry2x32(0u, 42u, 0u, 2u, ks0, ks1);

  // ---- frequency masks (shared across batch); thread b handles bin f=b ----
  // uf = uniform(kf, (2,2)) row-major: elements 0..3
  const float uf00 = u01(rbits(kf0, kf1, 0u));
  const float uf01 = u01(rbits(kf0, kf1, 1u));
  const float uf10 = u01(rbits(kf0, kf1, 2u));
  const float uf11 = u01(rbits(kf0, kf1, 3u));

  const float fv0 = __fmul_rn(uf00, 27.0f);
  const float fst0 = __fmul_rn(uf01, __fsub_rn(128.0f, fv0));
  const float fS0 = floorf(fst0);
  const float fE0 = floorf(__fadd_rn(fst0, fv0));

  const float fv1 = __fmul_rn(uf10, 27.0f);
  const float fst1 = __fmul_rn(uf11, __fsub_rn(128.0f, fv1));
  const float fS1 = floorf(fst1);
  const float fE1 = floorf(__fadd_rn(fst1, fv1));

  const float ff = (float)b;
  const bool fmask = (ff >= fS0 && ff < fE0) || (ff >= fS1 && ff < fE1);
  ws[b] = fmask ? 0.0f : 1.0f;

  // ---- time masks, per-sample adaptive ----
  const float xl = (float)x_len[b];
  const float tparam = floorf(__fmul_rn(0.25f, xl));

  // uv = uniform(kv, (128,2)), us = uniform(ks, (128,2)); element e = 2b+m
  const float uv0 = u01(rbits(kv0, kv1, (uint32_t)(2 * b)));
  const float uv1 = u01(rbits(kv0, kv1, (uint32_t)(2 * b + 1)));
  const float us0 = u01(rbits(ks0, ks1, (uint32_t)(2 * b)));
  const float us1 = u01(rbits(ks0, ks1, (uint32_t)(2 * b + 1)));

  const float tv0 = __fmul_rn(uv0, tparam);
  const float tst0 = __fmul_rn(us0, __fsub_rn(xl, tv0));
  const float TS0 = floorf(tst0);
  const float TE0 = floorf(__fadd_rn(tst0, tv0));

  const float tv1 = __fmul_rn(uv1, tparam);
  const float tst1 = __fmul_rn(us1, __fsub_rn(xl, tv1));
  const float TS1 = floorf(tst1);
  const float TE1 = floorf(__fadd_rn(tst1, tv1));

  float4* tse = (float4*)(ws + F_DIM);
  tse[b] = make_float4(TS0, TE0, TS1, TE1);
}

// Streaming apply:
//   grid = (T/32, B); block = 256 threads = 8 row-groups x 32 lanes.
//   Each block owns 32 contiguous rows of sample b = blockIdx.y (16 KiB).
//   Each thread handles rows t0 + 8*i (i=0..3), one float4 along F per row.
//   - b is a grid dim -> tse is a wave-uniform scalar load, no int division.
//   - time-masked rows: skip the x load entirely (saves ~8% of HBM traffic).
//   - nontemporal load/store: both streams are touch-once, bypass cache.
__global__ __launch_bounds__(256) void specaug_apply(
    const float* __restrict__ x, const float* __restrict__ ws,
    float* __restrict__ out) {
  const int lane = threadIdx.x & 31;   // float4 index along F
  const int rg = threadIdx.x >> 5;     // 0..7
  const int b = blockIdx.y;
  const int t0 = blockIdx.x * 32 + rg; // rows t0 + 8*i

  // Per-sample time-mask bounds: uniform across the block -> scalar loads.
  const f32x4 tse = *((const f32x4*)(ws + F_DIM) + b);
  // Per-lane frequency keep factors (L1-resident after first touch).
  const f32x4 fk = ((const f32x4*)ws)[lane];

  const size_t base = ((size_t)b * T_DIM + (size_t)t0) * F_DIM + (size_t)lane * 4;
  const float* xp = x + base;
  float* op = out + base;

#pragma unroll
  for (int i = 0; i < 4; ++i) {
    const float tf = (float)(t0 + 8 * i);
    const bool tmask = (tf >= tse.x && tf < tse.y) || (tf >= tse.z && tf < tse.w);
    const size_t off = (size_t)i * (8 * F_DIM);
    f32x4 o;
    if (tmask) {
      o.x = 0.0f; o.y = 0.0f; o.z = 0.0f; o.w = 0.0f;
    } else {
      const f32x4 v = __builtin_nontemporal_load((const f32x4*)(xp + off));
      o = v * fk;
    }
    __builtin_nontemporal_store(o, (f32x4*)(op + off));
  }
}

extern "C" void kernel_launch(void* const* d_in, const int* in_sizes, int n_in,
                              void* d_out, int out_size, void* d_ws, size_t ws_size,
                              hipStream_t stream) {
  const float* x = (const float*)d_in[0];
  const int* x_len = (const int*)d_in[1];
  float* out = (float*)d_out;
  float* ws = (float*)d_ws;

  specaug_setup<<<1, B_DIM, 0, stream>>>(x_len, ws);

  dim3 grid(T_DIM / 32, B_DIM);  // (125, 128)
  specaug_apply<<<grid, 256, 0, stream>>>(x, ws, out);
}